// Round 13
// baseline (361.756 us; speedup 1.0000x reference)
//
#include <hip/hip_runtime.h>

// LoRA MLP: out = silu_mul(x@(Wgu + Agu@Bgu)) @ (Wd + Ad@Bd)
// T=16384, D_MODEL=1024, D_FF=2816 (2*D_FF=5632), RANK=16
//
// R13: amortize the 2-phase overhead (m233): BK=64 per barrier (half the
// drains/FLOP), fat waves (4 x 128x128 output, 4 MFMA per ds_read_b128),
// 2-buf 64KB LDS x2 = 128KB, 1 block/CU, 1 wave/SIMD (~350 VGPR, lb(256,1)).
// Ledger (m97-style end-drain): iter kt: STAGE(kt+1->bufS); READ+MFMA(kt from
// bufR, two k32-halves); VMW(0); BARM; swap. RAW: stage(kt) drained at end of
// kt-1 + barrier. WAR: bufS last read at kt-1, complete before its MFMA &
// barrier. Swizzle: 8-chunk XOR (c ^= r&7) on DMA-source and read (involution)
// -> uniform 8 words/bank (structural floor).
// SGB: 16 VMEM; 16 DS(half0); {8 MFMA : 2 DS}x8; 64 MFMA -> half1 reads drain
// under half0 MFMA backlog.
//
// Workspace layout (bytes):
//   [0,            11534336)  Wgu_t  bf16 [5632][1024]
//   [11534336,     17301504)  Wd_t   bf16 [1024][2816]
//   [17301504,     50855936)  x_bf16      [16384][1024]
//   [50855936,    143130624)  h_bf16      [16384][2816]

typedef __bf16 bf16_t;
typedef __bf16 bf16x4 __attribute__((ext_vector_type(4)));
typedef __bf16 bf16x8 __attribute__((ext_vector_type(8)));
typedef float f32x4 __attribute__((ext_vector_type(4)));

#define TOKENS 16384
#define DMODEL 1024
#define DFF    2816
#define N2F    5632

#define BARM() asm volatile("s_barrier" ::: "memory")
#define VMW0() asm volatile("s_waitcnt vmcnt(0)" ::: "memory")
#define MFMA(d, va, vb) d = __builtin_amdgcn_mfma_f32_16x16x32_bf16(va, vb, d, 0, 0, 0)
#define LD8(p) (*(const bf16x8*)(p))
#define SGB(m, n) __builtin_amdgcn_sched_group_barrier(m, n, 0)
// per wave-iter: 16 VMEM(DMA), 32 DS_READ, 128 MFMA
#define SGB_PAT() do {                                                            \
    SGB(0x010, 16); SGB(0x100, 16);                                               \
    SGB(0x008, 8); SGB(0x100, 2); SGB(0x008, 8); SGB(0x100, 2);                   \
    SGB(0x008, 8); SGB(0x100, 2); SGB(0x008, 8); SGB(0x100, 2);                   \
    SGB(0x008, 8); SGB(0x100, 2); SGB(0x008, 8); SGB(0x100, 2);                   \
    SGB(0x008, 8); SGB(0x100, 2); SGB(0x008, 8); SGB(0x100, 2);                   \
    SGB(0x008, 64); } while (0)

__device__ __forceinline__ void gload16(const bf16_t* g, bf16_t* l) {
    __builtin_amdgcn_global_load_lds(
        (const __attribute__((address_space(1))) void*)g,
        (__attribute__((address_space(3))) void*)l, 16, 0, 0);
}

// ---------------------------------------------------------------------------
// W_eff_t[n][k] = bf16( W[k][n] + sum_r A[k][r]*B[r][n] )   (fp32 math)
template<int KTOT, int NTOT>
__global__ __launch_bounds__(256) void prep_weff(
        const float* __restrict__ W, const float* __restrict__ A,
        const float* __restrict__ B, bf16_t* __restrict__ Wt) {
    __shared__ float Ws[64][65];
    __shared__ float As[64][17];
    __shared__ float Bs[16][64];
    const int t = threadIdx.x;
    const int k0 = blockIdx.x * 64, n0 = blockIdx.y * 64;
    #pragma unroll
    for (int i = 0; i < 16; ++i) {
        int row = i * 4 + t / 64, col = t % 64;
        Ws[row][col] = W[(size_t)(k0 + row) * NTOT + n0 + col];
    }
    #pragma unroll
    for (int i = 0; i < 4; ++i) {
        int idx = i * 256 + t;
        As[idx / 16][idx % 16] = A[(size_t)(k0 + idx / 16) * 16 + idx % 16];
    }
    #pragma unroll
    for (int i = 0; i < 4; ++i) {
        int idx = i * 256 + t;
        Bs[idx / 64][idx % 64] = B[(size_t)(idx / 64) * NTOT + n0 + idx % 64];
    }
    __syncthreads();
    const int kl = t % 64;
    #pragma unroll
    for (int j = 0; j < 16; ++j) {
        int nl = j * 4 + t / 64;
        float val = Ws[kl][nl];
        #pragma unroll
        for (int r = 0; r < 16; ++r) val += As[kl][r] * Bs[r][nl];
        Wt[(size_t)(n0 + nl) * KTOT + k0 + kl] = (bf16_t)val;
    }
}

// ---------------------------------------------------------------------------
__global__ __launch_bounds__(256) void conv_bf16(
        const float* __restrict__ in, bf16_t* __restrict__ out, int n4) {
    int i = blockIdx.x * 256 + threadIdx.x;
    if (i < n4) {
        float4 v = ((const float4*)in)[i];
        bf16x4 o;
        o.x = (bf16_t)v.x; o.y = (bf16_t)v.y; o.z = (bf16_t)v.z; o.w = (bf16_t)v.w;
        ((bf16x4*)out)[i] = o;
    }
}

// ---------------------------------------------------------------------------
// GEMM1: h[T][DFF] = silu(g)*u, [g|u] = X[T][1024] @ Wgu_t^T
// Block 256(M) x 128(F)-dual; 4 waves 2M x 2F; wave 128 rows x 64 f x {g,u}.
// LDS buf (32768 bf16 = 64KB): A[256][64] @0, B[256][64] @16384
//   (B rows 0-127 = gate fbase+r, 128-255 = up DFF+fbase+r). 2 bufs = 128KB.
__global__ __launch_bounds__(256, 1) void gemm1(
        const bf16_t* __restrict__ X, const bf16_t* __restrict__ Wt,
        bf16_t* __restrict__ H) {
    __shared__ bf16_t lds[65536];
    const int t = threadIdx.x, l = t & 63;
    const int wid = t >> 6, wr = wid >> 1, wc = wid & 1;
    const int l15 = l & 15, lhi = l >> 4;
    const int wgl = ((int)blockIdx.x & 7) * 176 + ((int)blockIdx.x >> 3);
    const int tf = wgl % 22, tm = wgl / 22;
    const int mbase = tm * 256, fbase = tf * 128;
    // staging: thread t -> row sr = t>>3 (32 rows/call), chunk c = t&7 (16B)
    const int sr = t >> 3;
    const int scol = ((t & 7) ^ (sr & 7)) * 8;     // pre-swizzled global chunk
    // read-side: logical chunk (kh*4+lhi) at row r -> dest chunk ^ (r&7)
    const int swz0 = ((lhi ^ (l15 & 7))) * 8;
    const int aro = (wr * 128 + l15) * 64 + swz0;
    const int bro = (wc * 64 + l15) * 64 + swz0;   // gate rows; up: +8192

    f32x4 accg[8][4] = {}, accu[8][4] = {};
    bf16x8 a[8], bg[4], bu[4];
    bf16_t* bufR = lds;
    bf16_t* bufS = lds + 32768;
    const int NT1 = DMODEL / 64;  // 16

#define G1_STAGE(kt, buf) do { const int kc = (kt) * 64 + scol;                   \
    _Pragma("unroll")                                                             \
    for (int i = 0; i < 8; ++i)                                                   \
        gload16(X + (size_t)(mbase + i * 32 + sr) * DMODEL + kc,                  \
                (buf) + i * 2048 + t * 8);                                        \
    _Pragma("unroll")                                                             \
    for (int i = 0; i < 4; ++i)                                                   \
        gload16(Wt + (size_t)(fbase + i * 32 + sr) * DMODEL + kc,                 \
                (buf) + 16384 + i * 2048 + t * 8);                                \
    _Pragma("unroll")                                                             \
    for (int i = 0; i < 4; ++i)                                                   \
        gload16(Wt + (size_t)(DFF + fbase + i * 32 + sr) * DMODEL + kc,           \
                (buf) + 24576 + i * 2048 + t * 8); } while (0)
#define G1_READK(kh, buf) do { const int _x = (kh) * 32;                          \
    const bf16_t* _A = (buf);                                                     \
    a[0] = LD8(_A + (aro ^ _x));          a[1] = LD8(_A + (aro ^ _x) + 1024);     \
    a[2] = LD8(_A + (aro ^ _x) + 2048);   a[3] = LD8(_A + (aro ^ _x) + 3072);     \
    a[4] = LD8(_A + (aro ^ _x) + 4096);   a[5] = LD8(_A + (aro ^ _x) + 5120);     \
    a[6] = LD8(_A + (aro ^ _x) + 6144);   a[7] = LD8(_A + (aro ^ _x) + 7168);     \
    const bf16_t* _B = (buf) + 16384;                                             \
    bg[0] = LD8(_B + (bro ^ _x));         bg[1] = LD8(_B + (bro ^ _x) + 1024);    \
    bg[2] = LD8(_B + (bro ^ _x) + 2048);  bg[3] = LD8(_B + (bro ^ _x) + 3072);    \
    bu[0] = LD8(_B + (bro ^ _x) + 8192);  bu[1] = LD8(_B + (bro ^ _x) + 9216);    \
    bu[2] = LD8(_B + (bro ^ _x) + 10240); bu[3] = LD8(_B + (bro ^ _x) + 11264); } while (0)
#define G1_MFMAK() do {                                                           \
    _Pragma("unroll")                                                             \
    for (int m = 0; m < 8; ++m)                                                   \
        _Pragma("unroll")                                                         \
        for (int f = 0; f < 4; ++f) {                                             \
            MFMA(accg[m][f], a[m], bg[f]);                                        \
            MFMA(accu[m][f], a[m], bu[f]);                                        \
        } } while (0)

    G1_STAGE(0, bufR);
    VMW0(); BARM();
    for (int kt = 0; kt < NT1; ++kt) {
        if (kt + 1 < NT1) G1_STAGE(kt + 1, bufS);
        G1_READK(0, bufR); G1_MFMAK();
        G1_READK(1, bufR); G1_MFMAK();
        SGB_PAT();
        VMW0(); BARM();
        bf16_t* _tp = bufR; bufR = bufS; bufS = _tp;
    }
#undef G1_STAGE
#undef G1_READK
#undef G1_MFMAK

    #pragma unroll
    for (int m = 0; m < 8; ++m)
        #pragma unroll
        for (int f = 0; f < 4; ++f)
            #pragma unroll
            for (int r = 0; r < 4; ++r) {
                int row = mbase + wr * 128 + m * 16 + lhi * 4 + r;
                int col = fbase + wc * 64 + f * 16 + l15;
                float g = accg[m][f][r], u = accu[m][f][r];
                H[(size_t)row * DFF + col] = (bf16_t)(g / (1.0f + __expf(-g)) * u);
            }
}

// ---------------------------------------------------------------------------
// GEMM2: out[T][1024] = H[T][2816] @ Wd_t^T   (fp32 out)
// Block 256(M) x 256(N); 4 waves 2M x 2N; wave 128x128. Same R13 pipeline.
// LDS buf: A[256][64] @0, B[256][64] @16384. 2 bufs = 128KB. Grid 256 = 1/CU.
__global__ __launch_bounds__(256, 1) void gemm2(
        const bf16_t* __restrict__ Hm, const bf16_t* __restrict__ Wt,
        float* __restrict__ O) {
    __shared__ bf16_t lds[65536];
    const int t = threadIdx.x, l = t & 63;
    const int wid = t >> 6, wr = wid >> 1, wc = wid & 1;
    const int l15 = l & 15, lhi = l >> 4;
    const int wgl = ((int)blockIdx.x & 7) * 32 + ((int)blockIdx.x >> 3);
    const int tn = wgl % 4, tm = wgl / 4;
    const int mbase = tm * 256, nbase = tn * 256;
    const int sr = t >> 3;
    const int scol = ((t & 7) ^ (sr & 7)) * 8;
    const int swz0 = ((lhi ^ (l15 & 7))) * 8;
    const int aro = (wr * 128 + l15) * 64 + swz0;
    const int bro = (wc * 128 + l15) * 64 + swz0;

    f32x4 acc[8][8] = {};
    bf16x8 a[8], b[8];
    bf16_t* bufR = lds;
    bf16_t* bufS = lds + 32768;
    const int NT2 = DFF / 64;  // 44

#define G2_STAGE(kt, buf) do { const int kc = (kt) * 64 + scol;                   \
    _Pragma("unroll")                                                             \
    for (int i = 0; i < 8; ++i)                                                   \
        gload16(Hm + (size_t)(mbase + i * 32 + sr) * DFF + kc,                    \
                (buf) + i * 2048 + t * 8);                                        \
    _Pragma("unroll")                                                             \
    for (int i = 0; i < 8; ++i)                                                   \
        gload16(Wt + (size_t)(nbase + i * 32 + sr) * DFF + kc,                    \
                (buf) + 16384 + i * 2048 + t * 8); } while (0)
#define G2_READK(kh, buf) do { const int _x = (kh) * 32;                          \
    const bf16_t* _A = (buf);                                                     \
    a[0] = LD8(_A + (aro ^ _x));          a[1] = LD8(_A + (aro ^ _x) + 1024);     \
    a[2] = LD8(_A + (aro ^ _x) + 2048);   a[3] = LD8(_A + (aro ^ _x) + 3072);     \
    a[4] = LD8(_A + (aro ^ _x) + 4096);   a[5] = LD8(_A + (aro ^ _x) + 5120);     \
    a[6] = LD8(_A + (aro ^ _x) + 6144);   a[7] = LD8(_A + (aro ^ _x) + 7168);     \
    const bf16_t* _B = (buf) + 16384;                                             \
    b[0] = LD8(_B + (bro ^ _x));          b[1] = LD8(_B + (bro ^ _x) + 1024);     \
    b[2] = LD8(_B + (bro ^ _x) + 2048);   b[3] = LD8(_B + (bro ^ _x) + 3072);     \
    b[4] = LD8(_B + (bro ^ _x) + 4096);   b[5] = LD8(_B + (bro ^ _x) + 5120);     \
    b[6] = LD8(_B + (bro ^ _x) + 6144);   b[7] = LD8(_B + (bro ^ _x) + 7168); } while (0)
#define G2_MFMAK() do {                                                           \
    _Pragma("unroll")                                                             \
    for (int m = 0; m < 8; ++m)                                                   \
        _Pragma("unroll")                                                         \
        for (int n = 0; n < 8; ++n)                                               \
            MFMA(acc[m][n], a[m], b[n]); } while (0)

    G2_STAGE(0, bufR);
    VMW0(); BARM();
    for (int kt = 0; kt < NT2; ++kt) {
        if (kt + 1 < NT2) G2_STAGE(kt + 1, bufS);
        G2_READK(0, bufR); G2_MFMAK();
        G2_READK(1, bufR); G2_MFMAK();
        SGB_PAT();
        VMW0(); BARM();
        bf16_t* _tp = bufR; bufR = bufS; bufS = _tp;
    }
#undef G2_STAGE
#undef G2_READK
#undef G2_MFMAK

    #pragma unroll
    for (int m = 0; m < 8; ++m)
        #pragma unroll
        for (int n = 0; n < 8; ++n)
            #pragma unroll
            for (int r = 0; r < 4; ++r) {
                int row = mbase + wr * 128 + m * 16 + lhi * 4 + r;
                int col = nbase + wc * 128 + n * 16 + l15;
                O[(size_t)row * DMODEL + col] = acc[m][n][r];
            }
}

// ---------------------------------------------------------------------------
extern "C" void kernel_launch(void* const* d_in, const int* in_sizes, int n_in,
                              void* d_out, int out_size, void* d_ws, size_t ws_size,
                              hipStream_t stream) {
    const float* x   = (const float*)d_in[0];
    const float* Wgu = (const float*)d_in[1];
    const float* Agu = (const float*)d_in[2];
    const float* Bgu = (const float*)d_in[3];
    const float* Wd  = (const float*)d_in[4];
    const float* Ad  = (const float*)d_in[5];
    const float* Bd  = (const float*)d_in[6];
    float* out = (float*)d_out;
    char* ws = (char*)d_ws;

    bf16_t* wgut = (bf16_t*)(ws);                    // [5632][1024]
    bf16_t* wdt  = (bf16_t*)(ws + 11534336);         // [1024][2816]
    bf16_t* xb   = (bf16_t*)(ws + 17301504);         // [16384][1024]
    bf16_t* hb   = (bf16_t*)(ws + 50855936);         // [16384][2816]

    prep_weff<DMODEL, N2F><<<dim3(DMODEL / 64, N2F / 64), 256, 0, stream>>>(
        Wgu, Agu, Bgu, wgut);
    prep_weff<DFF, DMODEL><<<dim3(DFF / 64, DMODEL / 64), 256, 0, stream>>>(
        Wd, Ad, Bd, wdt);
    conv_bf16<<<(TOKENS * DMODEL / 4) / 256, 256, 0, stream>>>(
        x, xb, TOKENS * DMODEL / 4);
    gemm1<<<22 * 64, 256, 0, stream>>>(xb, wgut, hb);
    gemm2<<<4 * 64, 256, 0, stream>>>(hb, wdt, out);
}

// Round 14
// 330.526 us; speedup vs baseline: 1.0945x; 1.0945x over previous
//
#include <hip/hip_runtime.h>

// LoRA MLP: out = silu_mul(x@(Wgu + Agu@Bgu)) @ (Wd + Ad@Bd)
// T=16384, D_MODEL=1024, D_FF=2816 (2*D_FF=5632), RANK=16
//
// R14: R10 (best, 328us) + constant-folding unroll + tight setprio.
//  - gemm1: K-loop fully unrolled (29 uniform bodies + 3 peeled) -> all
//    buffer indices, register-set indices, DMA/ds offsets are literals.
//  - gemm2: manual x4 unroll (kt2%4==0 -> (kt+c)&3 literal) + peeled tails.
//  - setprio(1) around each 32-MFMA cluster (T5; SGB drift gives role-split).
// Ledger (R10, race-free): top of kt: VMW(4) retires stage(kt+1) [outstanding
// {kt+1,kt+2}=8]; BARM publishes; STAGE(kt+3); READ(buf kt+1); MFMA(kt).
// Peeled: kt=NT-3: VMW(4) retires NT-2's stage; kt=NT-2: VMW(0); kt=NT-1: MFMA.
//
// Workspace layout (bytes):
//   [0,            11534336)  Wgu_t  bf16 [5632][1024]
//   [11534336,     17301504)  Wd_t   bf16 [1024][2816]
//   [17301504,     50855936)  x_bf16      [16384][1024]
//   [50855936,    143130624)  h_bf16      [16384][2816]

typedef __bf16 bf16_t;
typedef __bf16 bf16x4 __attribute__((ext_vector_type(4)));
typedef __bf16 bf16x8 __attribute__((ext_vector_type(8)));
typedef float f32x4 __attribute__((ext_vector_type(4)));

#define TOKENS 16384
#define DMODEL 1024
#define DFF    2816
#define N2F    5632

#define BARM() asm volatile("s_barrier" ::: "memory")
#define VMW(n) asm volatile("s_waitcnt vmcnt(" #n ")" ::: "memory")
#define MFMA(d, va, vb) d = __builtin_amdgcn_mfma_f32_16x16x32_bf16(va, vb, d, 0, 0, 0)
#define LD8(p) (*(const bf16x8*)(p))
#define SGB(m, n) __builtin_amdgcn_sched_group_barrier(m, n, 0)
// per body: 4 VMEM(DMA), 12 DS_READ, 32 MFMA
#define SGB_PATTERN() do {                                                        \
    SGB(0x010, 4);                                                                \
    SGB(0x100, 2); SGB(0x008, 5);                                                 \
    SGB(0x100, 2); SGB(0x008, 5);                                                 \
    SGB(0x100, 2); SGB(0x008, 5);                                                 \
    SGB(0x100, 2); SGB(0x008, 5);                                                 \
    SGB(0x100, 2); SGB(0x008, 6);                                                 \
    SGB(0x100, 2); SGB(0x008, 6); } while (0)

__device__ __forceinline__ void gload16(const bf16_t* g, bf16_t* l) {
    __builtin_amdgcn_global_load_lds(
        (const __attribute__((address_space(1))) void*)g,
        (__attribute__((address_space(3))) void*)l, 16, 0, 0);
}

// ---------------------------------------------------------------------------
// W_eff_t[n][k] = bf16( W[k][n] + sum_r A[k][r]*B[r][n] )   (fp32 math)
template<int KTOT, int NTOT>
__global__ __launch_bounds__(256) void prep_weff(
        const float* __restrict__ W, const float* __restrict__ A,
        const float* __restrict__ B, bf16_t* __restrict__ Wt) {
    __shared__ float Ws[64][65];
    __shared__ float As[64][17];
    __shared__ float Bs[16][64];
    const int t = threadIdx.x;
    const int k0 = blockIdx.x * 64, n0 = blockIdx.y * 64;
    #pragma unroll
    for (int i = 0; i < 16; ++i) {
        int row = i * 4 + t / 64, col = t % 64;
        Ws[row][col] = W[(size_t)(k0 + row) * NTOT + n0 + col];
    }
    #pragma unroll
    for (int i = 0; i < 4; ++i) {
        int idx = i * 256 + t;
        As[idx / 16][idx % 16] = A[(size_t)(k0 + idx / 16) * 16 + idx % 16];
    }
    #pragma unroll
    for (int i = 0; i < 4; ++i) {
        int idx = i * 256 + t;
        Bs[idx / 64][idx % 64] = B[(size_t)(idx / 64) * NTOT + n0 + idx % 64];
    }
    __syncthreads();
    const int kl = t % 64;
    #pragma unroll
    for (int j = 0; j < 16; ++j) {
        int nl = j * 4 + t / 64;
        float val = Ws[kl][nl];
        #pragma unroll
        for (int r = 0; r < 16; ++r) val += As[kl][r] * Bs[r][nl];
        Wt[(size_t)(n0 + nl) * KTOT + k0 + kl] = (bf16_t)val;
    }
}

// ---------------------------------------------------------------------------
__global__ __launch_bounds__(256) void conv_bf16(
        const float* __restrict__ in, bf16_t* __restrict__ out, int n4) {
    int i = blockIdx.x * 256 + threadIdx.x;
    if (i < n4) {
        float4 v = ((const float4*)in)[i];
        bf16x4 o;
        o.x = (bf16_t)v.x; o.y = (bf16_t)v.y; o.z = (bf16_t)v.z; o.w = (bf16_t)v.w;
        ((bf16x4*)out)[i] = o;
    }
}

// ---------------------------------------------------------------------------
// GEMM1: h[T][DFF] = silu(g)*u, [g|u] = X[T][1024] @ Wgu_t^T
// Block 256(M) x 128(F)-dual; 8 waves 2M x 4F; wave = 128 rows x 32 f x {g,u}.
// Buf (16384 bf16 = 32KB): A[256][32] @0, Bg[128][32] @8192, Bu @12288.
// 4 bufs = 128KB. Fully unrolled K-loop (NT1 = 32).
__global__ __launch_bounds__(512, 2) void gemm1(
        const bf16_t* __restrict__ X, const bf16_t* __restrict__ Wt,
        bf16_t* __restrict__ H) {
    __shared__ bf16_t lds[65536];
    const int t = threadIdx.x, l = t & 63;
    const int wid = t >> 6, wr = wid >> 2, wc = wid & 3;
    const int l15 = l & 15, lhi = l >> 4;
    const int wgl = ((int)blockIdx.x & 7) * 176 + ((int)blockIdx.x >> 3);
    const int tf = wgl % 22, tm = wgl / 22;
    const int mbase = tm * 256, fbase = tf * 128;
    const int srow = t >> 2;
    const int sc8 = ((t & 3) ^ (srow & 3)) * 8;
    const bf16_t* gA  = X + (size_t)(mbase + srow) * DMODEL + sc8;
    const bf16_t* gA2 = gA + (size_t)128 * DMODEL;
    const bf16_t* gBg = Wt + (size_t)(fbase + srow) * DMODEL + sc8;
    const bf16_t* gBu = Wt + (size_t)(DFF + fbase + srow) * DMODEL + sc8;
    const int rsw = (lhi ^ (l15 & 3)) * 8;
    const int aoff = (wr * 128 + l15) * 32 + rsw;
    const int boff = 8192 + (wc * 32 + l15) * 32 + rsw;

    f32x4 accg[8][2] = {}, accu[8][2] = {};
    bf16x8 a[2][8], gg[2][2], uu[2][2];

#define G1_STAGE(kt) do {                                                         \
    bf16_t* p = lds + (((kt) & 3) << 14) + wid * 512;                             \
    gload16(gA  + (kt) * 32, p);                                                  \
    gload16(gA2 + (kt) * 32, p + 4096);                                           \
    gload16(gBg + (kt) * 32, p + 8192);                                           \
    gload16(gBu + (kt) * 32, p + 12288); } while (0)
#define G1_READ(s, bi) do {                                                       \
    const bf16_t* _pa = lds + ((bi) << 14) + aoff;                                \
    a[s][0] = LD8(_pa);        a[s][1] = LD8(_pa + 512);                          \
    a[s][2] = LD8(_pa + 1024); a[s][3] = LD8(_pa + 1536);                         \
    a[s][4] = LD8(_pa + 2048); a[s][5] = LD8(_pa + 2560);                         \
    a[s][6] = LD8(_pa + 3072); a[s][7] = LD8(_pa + 3584);                         \
    const bf16_t* _pb = lds + ((bi) << 14) + boff;                                \
    gg[s][0] = LD8(_pb);        gg[s][1] = LD8(_pb + 512);                        \
    uu[s][0] = LD8(_pb + 4096); uu[s][1] = LD8(_pb + 4608); } while (0)
#define G1_MFMA(s) do { __builtin_amdgcn_s_setprio(1);                            \
    _Pragma("unroll")                                                             \
    for (int m = 0; m < 8; ++m) {                                                 \
        MFMA(accg[m][0], a[s][m], gg[s][0]); MFMA(accu[m][0], a[s][m], uu[s][0]); \
        MFMA(accg[m][1], a[s][m], gg[s][1]); MFMA(accu[m][1], a[s][m], uu[s][1]); \
    }                                                                             \
    __builtin_amdgcn_s_setprio(0); } while (0)
// uniform body, kt = 0..28 (literal): stage kt+3, read kt+1, mfma kt
#define G1_BODY(kt)                                                               \
    VMW(4); BARM();                                                               \
    G1_STAGE((kt) + 3);                                                           \
    G1_READ(((kt) + 1) & 1, ((kt) + 1) & 3);                                      \
    G1_MFMA((kt) & 1);                                                            \
    SGB_PATTERN();

    G1_STAGE(0); G1_STAGE(1); G1_STAGE(2);
    VMW(8); BARM();
    G1_READ(0, 0);
    G1_BODY(0)  G1_BODY(1)  G1_BODY(2)  G1_BODY(3)  G1_BODY(4)  G1_BODY(5)
    G1_BODY(6)  G1_BODY(7)  G1_BODY(8)  G1_BODY(9)  G1_BODY(10) G1_BODY(11)
    G1_BODY(12) G1_BODY(13) G1_BODY(14) G1_BODY(15) G1_BODY(16) G1_BODY(17)
    G1_BODY(18) G1_BODY(19) G1_BODY(20) G1_BODY(21) G1_BODY(22) G1_BODY(23)
    G1_BODY(24) G1_BODY(25) G1_BODY(26) G1_BODY(27) G1_BODY(28)
    // kt = 29: no stage (29+3 > 31)
    VMW(4); BARM();
    G1_READ(0, 2);          // read tile 30 (set 0, buf 2)
    G1_MFMA(1);             // mfma tile 29
    // kt = 30
    VMW(0); BARM();
    G1_READ(1, 3);          // read tile 31 (set 1, buf 3)
    G1_MFMA(0);             // mfma tile 30
    // kt = 31
    G1_MFMA(1);
#undef G1_BODY
#undef G1_STAGE
#undef G1_READ
#undef G1_MFMA

    #pragma unroll
    for (int m = 0; m < 8; ++m)
        #pragma unroll
        for (int n = 0; n < 2; ++n)
            #pragma unroll
            for (int r = 0; r < 4; ++r) {
                int row = mbase + wr * 128 + m * 16 + lhi * 4 + r;
                int col = fbase + wc * 32 + n * 16 + l15;
                float g = accg[m][n][r], u = accu[m][n][r];
                H[(size_t)row * DFF + col] = (bf16_t)(g / (1.0f + __expf(-g)) * u);
            }
}

// ---------------------------------------------------------------------------
// GEMM2: out[T][1024] = H[T][2816] @ Wd_t^T   (fp32 out)
// Block 256(M) x 256(N); 8 waves 2M x 4N; wave 128x64. Manual x4 unroll
// (kt2 % 4 == 0 -> all buffer/set indices literal). NT2 = 88.
// Buf (16384 bf16): A[256][32] @0, B[256][32] @8192. 4 bufs = 128KB.
__global__ __launch_bounds__(512, 2) void gemm2(
        const bf16_t* __restrict__ Hm, const bf16_t* __restrict__ Wt,
        float* __restrict__ O) {
    __shared__ bf16_t lds[65536];
    const int t = threadIdx.x, l = t & 63;
    const int wid = t >> 6, wr = wid >> 2, wc = wid & 3;
    const int l15 = l & 15, lhi = l >> 4;
    const int wgl = ((int)blockIdx.x & 7) * 32 + ((int)blockIdx.x >> 3);
    const int tn = wgl % 4, tm = wgl / 4;
    const int mbase = tm * 256, nbase = tn * 256;
    const int srow = t >> 2;
    const int sc8 = ((t & 3) ^ (srow & 3)) * 8;
    const bf16_t* gA  = Hm + (size_t)(mbase + srow) * DFF + sc8;
    const bf16_t* gA2 = gA + (size_t)128 * DFF;
    const bf16_t* gB  = Wt + (size_t)(nbase + srow) * DFF + sc8;
    const bf16_t* gB2 = gB + (size_t)128 * DFF;
    const int rsw = (lhi ^ (l15 & 3)) * 8;
    const int aoff = (wr * 128 + l15) * 32 + rsw;
    const int boff = 8192 + (wc * 64 + l15) * 32 + rsw;

    f32x4 acc[8][4] = {};
    bf16x8 a[2][8], b[2][4];
    const int NT2 = DFF / 32;  // 88

#define G2_STAGE(kt, sb) do { const int kc = (kt) * 32;                           \
    bf16_t* p = lds + ((sb) << 14) + wid * 512;                                   \
    gload16(gA  + kc, p);                                                         \
    gload16(gA2 + kc, p + 4096);                                                  \
    gload16(gB  + kc, p + 8192);                                                  \
    gload16(gB2 + kc, p + 12288); } while (0)
#define G2_READ(s, bi) do {                                                       \
    const bf16_t* _pa = lds + ((bi) << 14) + aoff;                                \
    a[s][0] = LD8(_pa);        a[s][1] = LD8(_pa + 512);                          \
    a[s][2] = LD8(_pa + 1024); a[s][3] = LD8(_pa + 1536);                         \
    a[s][4] = LD8(_pa + 2048); a[s][5] = LD8(_pa + 2560);                         \
    a[s][6] = LD8(_pa + 3072); a[s][7] = LD8(_pa + 3584);                         \
    const bf16_t* _pb = lds + ((bi) << 14) + boff;                                \
    b[s][0] = LD8(_pb);        b[s][1] = LD8(_pb + 512);                          \
    b[s][2] = LD8(_pb + 1024); b[s][3] = LD8(_pb + 1536); } while (0)
#define G2_MFMA(s) do { __builtin_amdgcn_s_setprio(1);                            \
    _Pragma("unroll")                                                             \
    for (int m = 0; m < 8; ++m) {                                                 \
        MFMA(acc[m][0], a[s][m], b[s][0]); MFMA(acc[m][1], a[s][m], b[s][1]);     \
        MFMA(acc[m][2], a[s][m], b[s][2]); MFMA(acc[m][3], a[s][m], b[s][3]);     \
    }                                                                             \
    __builtin_amdgcn_s_setprio(0); } while (0)
// body: ms = kt&1 (mfma set), rs/rb = read set/buf for kt+1, sb = (kt+3)&3
#define G2_BODY(kt, ms, rs, rb, sb) do {                                          \
    VMW(4); BARM();                                                               \
    G2_STAGE((kt) + 3, sb);                                                       \
    G2_READ(rs, rb);                                                              \
    G2_MFMA(ms);                                                                  \
    SGB_PATTERN(); } while (0)

    G2_STAGE(0, 0); G2_STAGE(1, 1); G2_STAGE(2, 2);
    VMW(8); BARM();
    G2_READ(0, 0);
    for (int kt2 = 0; kt2 < 84; kt2 += 4) {
        G2_BODY(kt2 + 0, 0, 1, 1, 3);
        G2_BODY(kt2 + 1, 1, 0, 2, 0);
        G2_BODY(kt2 + 2, 0, 1, 3, 1);
        G2_BODY(kt2 + 3, 1, 0, 0, 2);
    }
    // kt = 84: stage 87 -> buf 3; read 85 (set 1, buf 1); mfma set 0
    VMW(4); BARM();
    G2_STAGE(87, 3);
    G2_READ(1, 1);
    G2_MFMA(0);
    SGB_PATTERN();
    // kt = 85: read 86 (set 0, buf 2); mfma set 1
    VMW(4); BARM();
    G2_READ(0, 2);
    G2_MFMA(1);
    // kt = 86: read 87 (set 1, buf 3); mfma set 0
    VMW(0); BARM();
    G2_READ(1, 3);
    G2_MFMA(0);
    // kt = 87
    G2_MFMA(1);
#undef G2_BODY
#undef G2_STAGE
#undef G2_READ
#undef G2_MFMA

    #pragma unroll
    for (int m = 0; m < 8; ++m)
        #pragma unroll
        for (int n = 0; n < 4; ++n)
            #pragma unroll
            for (int r = 0; r < 4; ++r) {
                int row = mbase + wr * 128 + m * 16 + lhi * 4 + r;
                int col = nbase + wc * 64 + n * 16 + l15;
                O[(size_t)row * DMODEL + col] = acc[m][n][r];
            }
}

// ---------------------------------------------------------------------------
extern "C" void kernel_launch(void* const* d_in, const int* in_sizes, int n_in,
                              void* d_out, int out_size, void* d_ws, size_t ws_size,
                              hipStream_t stream) {
    const float* x   = (const float*)d_in[0];
    const float* Wgu = (const float*)d_in[1];
    const float* Agu = (const float*)d_in[2];
    const float* Bgu = (const float*)d_in[3];
    const float* Wd  = (const float*)d_in[4];
    const float* Ad  = (const float*)d_in[5];
    const float* Bd  = (const float*)d_in[6];
    float* out = (float*)d_out;
    char* ws = (char*)d_ws;

    bf16_t* wgut = (bf16_t*)(ws);                    // [5632][1024]
    bf16_t* wdt  = (bf16_t*)(ws + 11534336);         // [1024][2816]
    bf16_t* xb   = (bf16_t*)(ws + 17301504);         // [16384][1024]
    bf16_t* hb   = (bf16_t*)(ws + 50855936);         // [16384][2816]

    prep_weff<DMODEL, N2F><<<dim3(DMODEL / 64, N2F / 64), 256, 0, stream>>>(
        Wgu, Agu, Bgu, wgut);
    prep_weff<DFF, DMODEL><<<dim3(DFF / 64, DMODEL / 64), 256, 0, stream>>>(
        Wd, Ad, Bd, wdt);
    conv_bf16<<<(TOKENS * DMODEL / 4) / 256, 256, 0, stream>>>(
        x, xb, TOKENS * DMODEL / 4);
    gemm1<<<22 * 64, 512, 0, stream>>>(xb, wgut, hb);
    gemm2<<<8 * 32, 512, 0, stream>>>(hb, wdt, out);
}